// Round 14
// baseline (87.997 us; speedup 1.0000x reference)
//
#include <hip/hip_runtime.h>

// StableContrastiveLoss on MI355X (gfx950).  B=4096, D=512, C=10, T=0.07.
// Round 14: R13 (fp8, 64x64 tiles, 2080 blocks, 2 waves, atomic-free P
// epilogue) with ONE change: staging engine DMA -> VALU uint4 loads +
// swizzled ds_write_b128. R1 measured 11.6 TB/s effective via VALU staging
// vs ~7 TB/s for global_load_lds DMA (R8/R9/R13); single-variable test of
// the engine term in the BW model. Bank check: per 16-lane write phase each
// of the 8 chunk-slots is written exactly 2x -> 2-way alias, free (m136).
// NEVER per-block __threadfence (R6).
// ws: F8[4096*512 fp8] | cls[4096] | P_all[64*64*64] | P_pos[...] | totals[2]

#define B_ROWS 4096
#define D_DIM  512
#define C_CLS  10
#define NT     64                     // 4096/64 tiles per dim
#define NTILES (NT * (NT + 1) / 2)    // 2080 upper-triangle tiles

typedef float f32x4 __attribute__((ext_vector_type(4)));

// ---------------- Kernel 1: normalize rows -> fp8, class extract -----------
__global__ __launch_bounds__(256) void prep_kernel(
    const float* __restrict__ feats, const float* __restrict__ labels,
    unsigned char* __restrict__ F8, int* __restrict__ cls,
    float* __restrict__ totals) {
  const int w = threadIdx.x >> 6, lane = threadIdx.x & 63;
  const int row = blockIdx.x * 4 + w;   // one wave per row
  const float* fr = feats + (size_t)row * D_DIM;
  float4 v0 = ((const float4*)fr)[2 * lane];
  float4 v1 = ((const float4*)fr)[2 * lane + 1];
  float ss = v0.x*v0.x + v0.y*v0.y + v0.z*v0.z + v0.w*v0.w
           + v1.x*v1.x + v1.y*v1.y + v1.z*v1.z + v1.w*v1.w;
  #pragma unroll
  for (int m = 1; m < 64; m <<= 1) ss += __shfl_xor(ss, m, 64);
  float inv = 1.0f / sqrtf(ss);

  // pack 8 normalized values into 8 fp8 e4m3 (OCP on gfx950)
  int p0 = __builtin_amdgcn_cvt_pk_fp8_f32(v0.x * inv, v0.y * inv, 0, 0);
  p0     = __builtin_amdgcn_cvt_pk_fp8_f32(v0.z * inv, v0.w * inv, p0, 1);
  int p1 = __builtin_amdgcn_cvt_pk_fp8_f32(v1.x * inv, v1.y * inv, 0, 0);
  p1     = __builtin_amdgcn_cvt_pk_fp8_f32(v1.z * inv, v1.w * inv, p1, 1);
  int2 pk; pk.x = p0; pk.y = p1;
  *(int2*)(F8 + (size_t)row * D_DIM + 8 * lane) = pk;

  float lv = (lane < C_CLS) ? labels[(size_t)row * C_CLS + lane] : 0.f;
  unsigned long long m = __ballot(lv > 0.5f);
  if (lane == 0) cls[row] = (int)(__ffsll((long long)m) - 1);
  if (blockIdx.x == 0 && threadIdx.x == 0) { totals[0] = 0.f; totals[1] = 0.f; }
}

// ------- Kernel 2: symmetric 64x64 fp8 sim, 2 waves, VALU staging ----------
// LDS tile: 64 rows x 128 B (BK=128 fp8), 8 chunks of 16B per row;
// LDS[row][c] = global chunk c^(row&7) (conflict-free b64 frag reads).
// Staging: thread t -> row t>>1, 64B half (t&1): 4 uint4 loads + 4 swizzled
// ds_write_b128 per operand per k0-iter.
__global__ __launch_bounds__(128) void sim_kernel(
    const unsigned char* __restrict__ F8, const int* __restrict__ cls,
    float* __restrict__ P_all, float* __restrict__ P_pos) {
  __shared__ __align__(16) unsigned char Abuf[64 * 128];
  __shared__ __align__(16) unsigned char Bbuf[64 * 128];
  __shared__ int clsA[64], clsB[64];
  __shared__ float g_row_all[64], g_row_pos[64];
  __shared__ float g_col_all[64], g_col_pos[64];

  // triangular tile decode (block-uniform scalar loop, <=64 iters)
  int rem = blockIdx.x, bi = 0, rowlen = NT;
  while (rem >= rowlen) { rem -= rowlen; ++bi; --rowlen; }
  const int bj = bi + rem;
  const int i0 = bi * 64, j0 = bj * 64;
  const bool offdiag = (bi != bj);

  const int t = threadIdx.x;       // 128 threads = 2 waves
  const int w = t >> 6;            // wave 0/1 -> rows 32w..32w+31
  const int lane = t & 63;
  const int q = lane >> 4;         // quad
  const int cl = lane & 15;

  if (t < 64) { clsA[t] = cls[i0 + t]; g_col_all[t] = 0.f; g_col_pos[t] = 0.f; }
  else        clsB[t - 64] = cls[j0 + t - 64];

  f32x4 acc[2][4];
  #pragma unroll
  for (int ri = 0; ri < 2; ++ri)
    #pragma unroll
    for (int c = 0; c < 4; ++c) acc[ri][c] = (f32x4){0.f, 0.f, 0.f, 0.f};

  // staging roles: thread t -> row t>>1 (0..63), 64B half (t&1)
  const int srow = t >> 1;
  const int sc0  = (t & 1) * 4;    // first of 4 consecutive 16B chunks

  for (int k0 = 0; k0 < D_DIM; k0 += 128) {   // 4 staging iters
    __syncthreads();  // previous readers done (covers cls/g_col init too)
    {
      const uint4* ga = (const uint4*)(F8 + (size_t)(i0 + srow) * D_DIM + k0 + sc0 * 16);
      const uint4* gb = (const uint4*)(F8 + (size_t)(j0 + srow) * D_DIM + k0 + sc0 * 16);
      uint4 a0 = ga[0], a1 = ga[1], a2 = ga[2], a3 = ga[3];
      uint4 b0 = gb[0], b1 = gb[1], b2 = gb[2], b3 = gb[3];
      const int sw = srow & 7;
      uint4* Ar = (uint4*)&Abuf[srow * 128];
      uint4* Br = (uint4*)&Bbuf[srow * 128];
      Ar[(sc0 + 0) ^ sw] = a0; Ar[(sc0 + 1) ^ sw] = a1;
      Ar[(sc0 + 2) ^ sw] = a2; Ar[(sc0 + 3) ^ sw] = a3;
      Br[(sc0 + 0) ^ sw] = b0; Br[(sc0 + 1) ^ sw] = b1;
      Br[(sc0 + 2) ^ sw] = b2; Br[(sc0 + 3) ^ sw] = b3;
    }
    __syncthreads();

    #pragma unroll
    for (int ks = 0; ks < 4; ++ks) {          // 4 k-steps of 32 fp8
      // frag = 8 fp8 at row-byte (ks*32 + q*8): chunk g = ks*2 + (q>>1),
      // 8B half h = q&1; swizzled LDS chunk = g ^ (row&7)
      const int g = ks * 2 + (q >> 1);
      const int h = (q & 1) * 8;
      long af[2]; long bf[4];
      #pragma unroll
      for (int ri = 0; ri < 2; ++ri) {
        const int row = 32 * w + 16 * ri + cl;
        af[ri] = *(const long*)&Abuf[row * 128 + ((g ^ (row & 7)) * 16) + h];
      }
      #pragma unroll
      for (int c = 0; c < 4; ++c) {
        const int row = 16 * c + cl;
        bf[c] = *(const long*)&Bbuf[row * 128 + ((g ^ (row & 7)) * 16) + h];
      }
      #pragma unroll
      for (int ri = 0; ri < 2; ++ri)
        #pragma unroll
        for (int c = 0; c < 4; ++c)
          acc[ri][c] = __builtin_amdgcn_mfma_f32_16x16x32_fp8_fp8(
              af[ri], bf[c], acc[ri][c], 0, 0, 0);
    }
  }

  // Epilogue. D layout (shape-determined, m89/m121): col=lane&15, row=q*4+reg.
  const float invT = 1.0f / 0.07f;
  float cs_all[4] = {0.f, 0.f, 0.f, 0.f};
  float cs_pos[4] = {0.f, 0.f, 0.f, 0.f};

  #pragma unroll
  for (int ri = 0; ri < 2; ++ri) {
    float sum_all[4] = {0.f, 0.f, 0.f, 0.f};
    float sum_pos[4] = {0.f, 0.f, 0.f, 0.f};
    #pragma unroll
    for (int c = 0; c < 4; ++c) {
      const int jloc = 16*c + cl;
      const int gj = j0 + jloc;
      const int cj = clsB[jloc];
      #pragma unroll
      for (int r = 0; r < 4; ++r) {
        const int iloc = 32*w + 16*ri + q*4 + r;
        const int gi = i0 + iloc;
        float s = acc[ri][c][r] * invT;
        s = fminf(fmaxf(s, -20.f), 20.f);
        const bool diag = (gi == gj);
        float e = diag ? 0.f : __expf(s);
        sum_all[r] += e;
        cs_all[c] += e;
        if (!diag && cj == clsA[iloc]) { sum_pos[r] += e; cs_pos[c] += e; }
      }
    }
    // row sums -> LDS (each row written exactly once: lanes cl==0)
    #pragma unroll
    for (int r = 0; r < 4; ++r) {
      float sa = sum_all[r], sp = sum_pos[r];
      #pragma unroll
      for (int m = 1; m < 16; m <<= 1) {
        sa += __shfl_xor(sa, m, 64);
        sp += __shfl_xor(sp, m, 64);
      }
      if (cl == 0) {
        const int rloc = 32*w + 16*ri + q*4 + r;
        g_row_all[rloc] = sa;
        g_row_pos[rloc] = sp;
      }
    }
  }

  // col sums: reduce across quads, then LDS-scope atomic combine of 2 waves
  if (offdiag) {
    #pragma unroll
    for (int c = 0; c < 4; ++c) {
      float sa = cs_all[c], sp = cs_pos[c];
      sa += __shfl_xor(sa, 16, 64); sa += __shfl_xor(sa, 32, 64);
      sp += __shfl_xor(sp, 16, 64); sp += __shfl_xor(sp, 32, 64);
      if (q == 0) {
        atomicAdd(&g_col_all[16*c + cl], sa);
        atomicAdd(&g_col_pos[16*c + cl], sp);
      }
    }
  }
  __syncthreads();

  // store phase: coalesced 256B stores, exactly-once slot coverage
  if (w == 0) {
    const size_t base_row = ((size_t)bi * 64 + bj) * 64;
    P_all[base_row + lane] = g_row_all[lane];
    P_pos[base_row + lane] = g_row_pos[lane];
  } else if (offdiag) {
    const size_t base_col = ((size_t)bj * 64 + bi) * 64;
    P_all[base_col + lane] = g_col_all[lane];
    P_pos[base_col + lane] = g_col_pos[lane];
  }
}

// ---- Kernel 3: per-strip reduction (64 blocks), tiny atomics to totals ----
__global__ __launch_bounds__(256) void finalize_kernel(
    const float* __restrict__ P_all, const float* __restrict__ P_pos,
    float* __restrict__ totals) {
  __shared__ float Sall[4096], Spos[4096];   // 32 KB
  const int s = blockIdx.x;
  const int t = threadIdx.x;
  for (int i = t; i < 4096; i += 256) {
    Sall[i] = P_all[(size_t)s * 4096 + i];   // coalesced
    Spos[i] = P_pos[(size_t)s * 4096 + i];
  }
  __syncthreads();
  if (t < 64) {   // wave 0: row r = t of this strip
    float a = 0.f, p = 0.f;
    #pragma unroll 8
    for (int k = 0; k < 64; ++k) {   // column sum: 2-way bank alias (free)
      a += Sall[k * 64 + t];
      p += Spos[k * 64 + t];
    }
    float loss = 0.f, cnt = 0.f;
    if (p > 0.f) {                   // valid iff >=1 positive
      loss = -logf(p / (a + 1e-8f) + 1e-8f);
      cnt = 1.f;
    }
    #pragma unroll
    for (int m = 1; m < 64; m <<= 1) {
      loss += __shfl_xor(loss, m, 64);
      cnt  += __shfl_xor(cnt, m, 64);
    }
    if (t == 0) {                    // 128 atomics total across the grid
      atomicAdd(&totals[0], loss);
      atomicAdd(&totals[1], cnt);
    }
  }
}

// ---------------- Kernel 4: scalar division ----------------
__global__ void div_kernel(const float* __restrict__ totals,
                           float* __restrict__ out) {
  out[0] = (totals[1] > 0.f) ? (totals[0] / totals[1]) : 0.f;
}

extern "C" void kernel_launch(void* const* d_in, const int* in_sizes, int n_in,
                              void* d_out, int out_size, void* d_ws, size_t ws_size,
                              hipStream_t stream) {
  const float* features = (const float*)d_in[0];
  const float* labels   = (const float*)d_in[1];
  float* out = (float*)d_out;

  unsigned char* F8     = (unsigned char*)d_ws;
  int*    cls    = (int*)((char*)d_ws + (size_t)B_ROWS * D_DIM);
  float*  P_all  = (float*)((char*)cls + B_ROWS * sizeof(int));
  float*  P_pos  = P_all + (size_t)NT * NT * 64;
  float*  totals = P_pos + (size_t)NT * NT * 64;

  prep_kernel<<<B_ROWS / 4, 256, 0, stream>>>(features, labels, F8, cls, totals);
  sim_kernel<<<NTILES, 128, 0, stream>>>(F8, cls, P_all, P_pos);
  finalize_kernel<<<NT, 256, 0, stream>>>(P_all, P_pos, totals);
  div_kernel<<<1, 1, 0, stream>>>(totals, out);
}